// Round 5
// baseline (126.404 us; speedup 1.0000x reference)
//
#include <hip/hip_runtime.h>

#define BTOT 65536
#define TST  28
#define PACK_DW 180   // dwords per lane in packed-weight workspace

typedef __attribute__((ext_vector_type(8))) short bf16x8;
typedef __attribute__((ext_vector_type(4))) float f32x4;
typedef __attribute__((ext_vector_type(2))) unsigned int u32x2;

__device__ __forceinline__ unsigned int f2bf(float f) {
    unsigned u = __float_as_uint(f);
    u += 0x7fff + ((u >> 16) & 1);   // RNE
    return u >> 16;
}

// Pack all weights into per-lane MFMA fragment layout (bf16), plus b3 (f32).
// Wx = W1 @ W2a padded to 32 rows; row 28 = c = b2 + b1@W2a (bias-via-MFMA with
// x-frag element k=28 forced to 1.0); rows 29..31 = 0.
// Per-lane dword layout: [0..127] W2b frags (kk,t) | [128..159] Wx frags (t)
//                        [160..175] W3 frags (kk)  | [176..179] b3 (f32)
__global__ void pack_kernel(const float* __restrict__ W1, const float* __restrict__ b1,
                            const float* __restrict__ W2, const float* __restrict__ b2,
                            const float* __restrict__ W3, const float* __restrict__ b3,
                            unsigned int* __restrict__ wsPack) {
    __shared__ float WxL[32][128];
    const int tid = threadIdx.x;
    for (int e = tid; e < 32 * 128; e += 256) {
        const int k = e >> 7, n = e & 127;
        float s = 0.f;
        if (k < 28) {
            for (int m = 0; m < 128; ++m) s += W1[k * 128 + m] * W2[m * 128 + n];
        } else if (k == 28) {
            s = b2[n];
            for (int m = 0; m < 128; ++m) s += b1[m] * W2[m * 128 + n];
        }
        WxL[k][n] = s;
    }
    __syncthreads();
    if (tid < 64) {
        const int lr = tid & 15, kh = tid >> 4;
        unsigned int* P = wsPack + tid * PACK_DW;
        // W2b: A-frag of W2b^T — element j of frag(kk,t) = W2[128+32kk+8kh+j][16t+lr]
        for (int kk = 0; kk < 4; ++kk)
            for (int t = 0; t < 8; ++t)
                for (int jd = 0; jd < 4; ++jd) {
                    const int k = 128 + kk * 32 + kh * 8 + jd * 2;
                    const int n = t * 16 + lr;
                    P[(kk * 8 + t) * 4 + jd] =
                        f2bf(W2[k * 128 + n]) | (f2bf(W2[(k + 1) * 128 + n]) << 16);
                }
        // Wx frags: element j of frag(t) = Wx[8kh+j][16t+lr]
        for (int t = 0; t < 8; ++t)
            for (int jd = 0; jd < 4; ++jd) {
                const int k = kh * 8 + jd * 2;
                const int n = t * 16 + lr;
                P[128 + t * 4 + jd] = f2bf(WxL[k][n]) | (f2bf(WxL[k + 1][n]) << 16);
            }
        // W3 frags: element j of frag(kk) = W3[32kk+8kh+j][lr] (lr<10 else 0)
        for (int kk = 0; kk < 4; ++kk)
            for (int jd = 0; jd < 4; ++jd) {
                const int k = kk * 32 + kh * 8 + jd * 2;
                unsigned lo = (lr < 10) ? f2bf(W3[k * 10 + lr]) : 0u;
                unsigned hi = (lr < 10) ? f2bf(W3[(k + 1) * 10 + lr]) : 0u;
                P[160 + kk * 4 + jd] = lo | (hi << 16);
            }
        // b3 as f32, indexed by output row o = 4kh+j of the D^T epilogue tile
        for (int j = 0; j < 4; ++j) {
            const int o = kh * 4 + j;
            P[176 + j] = __float_as_uint((o < 10) ? b3[o] : 0.f);
        }
    }
}

__device__ __forceinline__ bf16x8 cvt8(f32x4 a, f32x4 b) {
    union { unsigned int u[4]; bf16x8 v; } r;
    asm("v_cvt_pk_bf16_f32 %0, %1, %2" : "=v"(r.u[0]) : "v"(a[0]), "v"(a[1]));
    asm("v_cvt_pk_bf16_f32 %0, %1, %2" : "=v"(r.u[1]) : "v"(a[2]), "v"(a[3]));
    asm("v_cvt_pk_bf16_f32 %0, %1, %2" : "=v"(r.u[2]) : "v"(b[0]), "v"(b[1]));
    asm("v_cvt_pk_bf16_f32 %0, %1, %2" : "=v"(r.u[3]) : "v"(b[2]), "v"(b[3]));
    return r.v;
}

// Each wave owns 16 batch rows and ALL 128 hidden cols: no inter-wave sharing,
// no barriers in the time loop. h round-trips through a wave-private LDS slice
// only to convert D-layout -> B-frag layout.
__global__ __launch_bounds__(256, 2) void rnn_kernel(
    const float* __restrict__ x, const unsigned int* __restrict__ wsPack,
    float* __restrict__ out)
{
    __shared__ short Hs[4][16][136];   // per-wave [16 rows][128 + 8 pad]
    const int tid = threadIdx.x;
    const int w = tid >> 6, lane = tid & 63, lr = lane & 15, kh = lane >> 4;
    const int r0 = blockIdx.x * 64 + w * 16;

    const unsigned int* P = wsPack + lane * PACK_DW;
    bf16x8 w2b[4][8], wx[8];
    #pragma unroll
    for (int kk = 0; kk < 4; ++kk)
        #pragma unroll
        for (int t = 0; t < 8; ++t)
            w2b[kk][t] = *(const bf16x8*)(P + (kk * 8 + t) * 4);
    #pragma unroll
    for (int t = 0; t < 8; ++t) wx[t] = *(const bf16x8*)(P + 128 + t * 4);

    // h0 = 0 (wave-private region; in-wave LDS ordering suffices)
    unsigned int* hz = (unsigned int*)&Hs[w][0][0];
    #pragma unroll
    for (int i = 0; i < 17; ++i) hz[lane + i * 64] = 0u;

    // x B-frag source: lane reads x[r0+lr][28t + 8kh + j]; kh==3 upper half is
    // {1.0 (k=28, bias hook), 0,0,0} — Wx rows 29..31 are zero so tail is inert.
    const float* xr = x + (size_t)(r0 + lr) * 784 + 8 * kh;
    f32x4 xa = *(const f32x4*)xr;
    f32x4 xc = (kh < 3) ? *(const f32x4*)(xr + 4) : (f32x4){1.f, 0.f, 0.f, 0.f};
    bf16x8 xb = cvt8(xa, xc);
    const f32x4 z4 = {0.f, 0.f, 0.f, 0.f};

    for (int t = 0; t < TST; ++t) {
        f32x4 acc[8];
        // x part (carries bias via Wx row 28)
        #pragma unroll
        for (int t8 = 0; t8 < 8; ++t8)
            acc[t8] = __builtin_amdgcn_mfma_f32_16x16x32_bf16(wx[t8], xb, z4, 0, 0, 0);
        // prefetch next x under the MFMAs
        f32x4 na, nc;
        if (t + 1 < TST) {
            const float* xp = xr + (t + 1) * 28;
            na = *(const f32x4*)xp;
            nc = (kh < 3) ? *(const f32x4*)(xp + 4) : (f32x4){1.f, 0.f, 0.f, 0.f};
        }
        // h part: B-frag of h^T = 16B row-reads of wave-private H
        bf16x8 hbv[4];
        #pragma unroll
        for (int kk = 0; kk < 4; ++kk)
            hbv[kk] = *(const bf16x8*)&Hs[w][lr][kk * 32 + kh * 8];
        #pragma unroll
        for (int kk = 0; kk < 4; ++kk)
            #pragma unroll
            for (int t8 = 0; t8 < 8; ++t8)
                acc[t8] = __builtin_amdgcn_mfma_f32_16x16x32_bf16(w2b[kk][t8], hbv[kk], acc[t8], 0, 0, 0);
        // relu + pack 4 consecutive n per lane -> one 8B store
        #pragma unroll
        for (int t8 = 0; t8 < 8; ++t8) {
            f32x4 v = acc[t8];
            v[0] = fmaxf(v[0], 0.f); v[1] = fmaxf(v[1], 0.f);
            v[2] = fmaxf(v[2], 0.f); v[3] = fmaxf(v[3], 0.f);
            unsigned lo, hi;
            asm("v_cvt_pk_bf16_f32 %0, %1, %2" : "=v"(lo) : "v"(v[0]), "v"(v[1]));
            asm("v_cvt_pk_bf16_f32 %0, %1, %2" : "=v"(hi) : "v"(v[2]), "v"(v[3]));
            u32x2 st = {lo, hi};
            *(u32x2*)&Hs[w][lr][t8 * 16 + kh * 4] = st;
        }
        if (t + 1 < TST) xb = cvt8(na, nc);
    }

    // epilogue: out^T tile = W3^T . h^T + b3
    bf16x8 w3f[4];
    #pragma unroll
    for (int kk = 0; kk < 4; ++kk) w3f[kk] = *(const bf16x8*)(P + 160 + kk * 4);
    const float* bp = (const float*)(P + 176);
    f32x4 accO = {bp[0], bp[1], bp[2], bp[3]};
    #pragma unroll
    for (int kk = 0; kk < 4; ++kk) {
        bf16x8 hb = *(const bf16x8*)&Hs[w][lr][kk * 32 + kh * 8];
        accO = __builtin_amdgcn_mfma_f32_16x16x32_bf16(w3f[kk], hb, accO, 0, 0, 0);
    }
    float* op = out + (size_t)(r0 + lr) * 10 + kh * 4;
    #pragma unroll
    for (int j = 0; j < 4; ++j)
        if (kh * 4 + j < 10) op[j] = accO[j];
}

extern "C" void kernel_launch(void* const* d_in, const int* in_sizes, int n_in,
                              void* d_out, int out_size, void* d_ws, size_t ws_size,
                              hipStream_t stream) {
    const float* x  = (const float*)d_in[0];
    const float* W1 = (const float*)d_in[1];
    const float* b1 = (const float*)d_in[2];
    const float* W2 = (const float*)d_in[3];
    const float* b2 = (const float*)d_in[4];
    const float* W3 = (const float*)d_in[5];
    const float* b3 = (const float*)d_in[6];
    unsigned int* wsPack = (unsigned int*)d_ws;   // 64 lanes * 180 dwords = 45 KiB

    pack_kernel<<<1, 256, 0, stream>>>(W1, b1, W2, b2, W3, b3, wsPack);
    rnn_kernel<<<BTOT / 64, 256, 0, stream>>>(x, wsPack, (float*)d_out);
}

// Round 6
// 80.384 us; speedup vs baseline: 1.5725x; 1.5725x over previous
//
#include <hip/hip_runtime.h>

#define BTOT 65536
#define TST  28
#define PACK_DW 100
// ws layout (dwords): [0 .. 12800) packed frags (2 p-variants x 64 lanes x 100)
//                     [12800 .. 16896) WxL: 32 x 128 f32 (rows 29..31 zeroed)
#define WXL_OFF 12800

typedef __attribute__((ext_vector_type(8))) short bf16x8;
typedef __attribute__((ext_vector_type(4))) float f32x4;
typedef __attribute__((ext_vector_type(2))) unsigned int u32x2;

__device__ __forceinline__ unsigned int f2bf(float f) {
    unsigned u = __float_as_uint(f);
    u += 0x7fff + ((u >> 16) & 1);   // RNE
    return u >> 16;
}
__device__ __forceinline__ unsigned int pk2bf(float a, float b) {
    return f2bf(a) | (f2bf(b) << 16);
}
__device__ __forceinline__ bf16x8 cvt8(f32x4 a, f32x4 b) {
    union { unsigned int u[4]; bf16x8 v; } r;
    asm("v_cvt_pk_bf16_f32 %0, %1, %2" : "=v"(r.u[0]) : "v"(a[0]), "v"(a[1]));
    asm("v_cvt_pk_bf16_f32 %0, %1, %2" : "=v"(r.u[1]) : "v"(a[2]), "v"(a[3]));
    asm("v_cvt_pk_bf16_f32 %0, %1, %2" : "=v"(r.u[2]) : "v"(b[0]), "v"(b[1]));
    asm("v_cvt_pk_bf16_f32 %0, %1, %2" : "=v"(r.u[3]) : "v"(b[2]), "v"(b[3]));
    return r.v;
}

// pack1: blocks 0..28 compute WxL row k (Wx = W1@W2a; row 28 = b2 + b1@W2a, the
// bias row hit by x-frag element k=28 := 1.0; block 28 also zeroes rows 29..31).
// Block 29 packs W2b A-frags (both p-halves); block 30 packs W3 frags + b3.
__global__ void pack1(const float* __restrict__ W1, const float* __restrict__ b1,
                      const float* __restrict__ W2, const float* __restrict__ b2,
                      const float* __restrict__ W3, const float* __restrict__ b3,
                      unsigned int* __restrict__ ws) {
    float* WxL = (float*)(ws + WXL_OFF);
    const int bid = blockIdx.x, tid = threadIdx.x;
    if (bid < 29) {
        const int k = bid, n = tid;   // 128 threads
        float s = 0.f;
        if (k < 28) {
            for (int m = 0; m < 128; ++m) s += W1[k * 128 + m] * W2[m * 128 + n];
        } else {
            s = b2[n];
            for (int m = 0; m < 128; ++m) s += b1[m] * W2[m * 128 + n];
        }
        WxL[k * 128 + n] = s;
        if (k == 28) { WxL[29*128+n] = 0.f; WxL[30*128+n] = 0.f; WxL[31*128+n] = 0.f; }
    } else if (bid == 29) {
        if (tid < 64) {
            const int lr = tid & 15, kh = tid >> 4;
            for (int p = 0; p < 2; ++p) {
                unsigned int* P = ws + (p * 64 + tid) * PACK_DW;
                for (int kk = 0; kk < 4; ++kk)
                    for (int t = 0; t < 4; ++t)
                        for (int jd = 0; jd < 4; ++jd) {
                            const int k = 128 + kk * 32 + kh * 8 + jd * 2;
                            const int n = p * 64 + t * 16 + lr;
                            P[(kk * 4 + t) * 4 + jd] =
                                pk2bf(W2[k * 128 + n], W2[(k + 1) * 128 + n]);
                        }
            }
        }
    } else {
        if (tid < 64) {
            const int lr = tid & 15, kh = tid >> 4;
            unsigned int* P = ws + tid * PACK_DW;   // p=0 rows only (epilogue wave)
            for (int kk = 0; kk < 4; ++kk)
                for (int jd = 0; jd < 4; ++jd) {
                    const int k = kk * 32 + kh * 8 + jd * 2;
                    float lo = (lr < 10) ? W3[k * 10 + lr] : 0.f;
                    float hi = (lr < 10) ? W3[(k + 1) * 10 + lr] : 0.f;
                    P[80 + kk * 4 + jd] = pk2bf(lo, hi);
                }
            for (int j = 0; j < 4; ++j) {
                const int o = kh * 4 + j;
                P[96 + j] = __float_as_uint((o < 10) ? b3[o] : 0.f);
            }
        }
    }
}

// pack2: Wx A-frags (needs WxL from pack1's blocks 0..28).
__global__ void pack2(unsigned int* __restrict__ ws) {
    const int tid = threadIdx.x;
    if (tid < 64) {
        const float* WxL = (const float*)(ws + WXL_OFF);
        const int lr = tid & 15, kh = tid >> 4;
        for (int p = 0; p < 2; ++p) {
            unsigned int* P = ws + (p * 64 + tid) * PACK_DW;
            for (int t = 0; t < 4; ++t)
                for (int jd = 0; jd < 4; ++jd) {
                    const int k = kh * 8 + jd * 2, n = p * 64 + t * 16 + lr;
                    P[64 + t * 4 + jd] = pk2bf(WxL[k * 128 + n], WxL[(k + 1) * 128 + n]);
                }
        }
    }
}

// Block = 2 teams x 2 waves. Team owns 16 batch rows; wave p owns n-half
// [64p,64p+64). H double-buffered in LDS (bf16), ONE barrier per step.
// Weights: W2b half (64 VGPR) + Wx half (16) register-resident per wave.
__global__ __launch_bounds__(256, 3) void rnn_kernel(
    const float* __restrict__ x, const unsigned int* __restrict__ wsPack,
    float* __restrict__ out)
{
    __shared__ __align__(16) short Hs[2][2][16][136];  // [team][buf][batch][n+pad]
    const int tid = threadIdx.x;
    const int w = tid >> 6, lane = tid & 63, lr = lane & 15, kh = lane >> 4;
    const int g = w >> 1, p = w & 1;
    const int r0 = blockIdx.x * 32 + g * 16;

    const unsigned int* P = wsPack + (p * 64 + lane) * PACK_DW;
    bf16x8 w2b[4][4], wx[4];
    #pragma unroll
    for (int kk = 0; kk < 4; ++kk)
        #pragma unroll
        for (int t = 0; t < 4; ++t)
            w2b[kk][t] = *(const bf16x8*)(P + (kk * 4 + t) * 4);
    #pragma unroll
    for (int t = 0; t < 4; ++t) wx[t] = *(const bf16x8*)(P + 64 + t * 4);

    // zero buf0 (zero the whole region; 4352 dwords / 256 threads = 17 each)
    unsigned int* hz = (unsigned int*)&Hs[0][0][0][0];
    #pragma unroll
    for (int i = 0; i < 17; ++i) hz[tid + i * 256] = 0u;
    __syncthreads();

    // x B-frag: lane (kh,lr) reads x[r0+lr][28t + 8kh + j]; kh==3 upper half is
    // {1.0 (k=28 bias hook), 0,0,0} — Wx rows 29..31 are zero.
    const float* xr = x + (size_t)(r0 + lr) * 784 + 8 * kh;
    f32x4 xa = *(const f32x4*)xr;
    f32x4 xc = (kh < 3) ? *(const f32x4*)(xr + 4) : (f32x4){1.f, 0.f, 0.f, 0.f};
    bf16x8 xb = cvt8(xa, xc);
    const f32x4 z4 = {0.f, 0.f, 0.f, 0.f};

    int cur = 0;
    for (int t = 0; t < TST; ++t) {
        f32x4 acc[4];
        // x part (bias rides in Wx row 28)
        #pragma unroll
        for (int t4 = 0; t4 < 4; ++t4)
            acc[t4] = __builtin_amdgcn_mfma_f32_16x16x32_bf16(wx[t4], xb, z4, 0, 0, 0);
        // prefetch next x under the MFMAs
        f32x4 na, nc;
        if (t + 1 < TST) {
            const float* xp = xr + (t + 1) * 28;
            na = *(const f32x4*)xp;
            nc = (kh < 3) ? *(const f32x4*)(xp + 4) : (f32x4){1.f, 0.f, 0.f, 0.f};
        }
        // h B-frags: 4x b128 row-reads (bank-uniform)
        bf16x8 hbv[4];
        #pragma unroll
        for (int kk = 0; kk < 4; ++kk)
            hbv[kk] = *(const bf16x8*)&Hs[g][cur][lr][kk * 32 + kh * 8];
        #pragma unroll
        for (int kk = 0; kk < 4; ++kk)
            #pragma unroll
            for (int t4 = 0; t4 < 4; ++t4)
                acc[t4] = __builtin_amdgcn_mfma_f32_16x16x32_bf16(w2b[kk][t4], hbv[kk], acc[t4], 0, 0, 0);
        // relu + pack -> one 8B store per t4 (n-rows 64p+16t4+4kh+0..3, batch lr)
        #pragma unroll
        for (int t4 = 0; t4 < 4; ++t4) {
            f32x4 v = acc[t4];
            v[0] = fmaxf(v[0], 0.f); v[1] = fmaxf(v[1], 0.f);
            v[2] = fmaxf(v[2], 0.f); v[3] = fmaxf(v[3], 0.f);
            unsigned lo, hi;
            asm("v_cvt_pk_bf16_f32 %0, %1, %2" : "=v"(lo) : "v"(v[0]), "v"(v[1]));
            asm("v_cvt_pk_bf16_f32 %0, %1, %2" : "=v"(hi) : "v"(v[2]), "v"(v[3]));
            u32x2 st = {lo, hi};
            *(u32x2*)&Hs[g][cur ^ 1][lr][p * 64 + t4 * 16 + kh * 4] = st;
        }
        if (t + 1 < TST) xb = cvt8(na, nc);
        __syncthreads();
        cur ^= 1;
    }

    // epilogue: p==0 wave of each team computes out^T = W3^T.h^T + b3
    if (p == 0) {
        bf16x8 w3f[4];
        #pragma unroll
        for (int kk = 0; kk < 4; ++kk) w3f[kk] = *(const bf16x8*)(P + 80 + kk * 4);
        const float* bp = (const float*)(P + 96);
        f32x4 accO = {bp[0], bp[1], bp[2], bp[3]};
        #pragma unroll
        for (int kk = 0; kk < 4; ++kk) {
            bf16x8 hb = *(const bf16x8*)&Hs[g][cur][lr][kk * 32 + kh * 8];
            accO = __builtin_amdgcn_mfma_f32_16x16x32_bf16(w3f[kk], hb, accO, 0, 0, 0);
        }
        float* op = out + (size_t)(r0 + lr) * 10 + kh * 4;
        #pragma unroll
        for (int j = 0; j < 4; ++j)
            if (kh * 4 + j < 10) op[j] = accO[j];
    }
}

extern "C" void kernel_launch(void* const* d_in, const int* in_sizes, int n_in,
                              void* d_out, int out_size, void* d_ws, size_t ws_size,
                              hipStream_t stream) {
    const float* x  = (const float*)d_in[0];
    const float* W1 = (const float*)d_in[1];
    const float* b1 = (const float*)d_in[2];
    const float* W2 = (const float*)d_in[3];
    const float* b2 = (const float*)d_in[4];
    const float* W3 = (const float*)d_in[5];
    const float* b3 = (const float*)d_in[6];
    unsigned int* ws = (unsigned int*)d_ws;   // 16896 dwords = 66 KiB

    pack1<<<31, 128, 0, stream>>>(W1, b1, W2, b2, W3, b3, ws);
    pack2<<<1, 64, 0, stream>>>(ws);
    rnn_kernel<<<BTOT / 32, 256, 0, stream>>>(x, ws, (float*)d_out);
}